// Round 2
// baseline (551.977 us; speedup 1.0000x reference)
//
#include <hip/hip_runtime.h>
#include <hip/hip_bf16.h>
#include <stdint.h>

typedef __attribute__((ext_vector_type(8))) short short8;
typedef __attribute__((ext_vector_type(16))) float f32x16;

#define CD 256   // channels
#define HD 512   // hidden

// ---------- helpers ----------
static __device__ __forceinline__ unsigned short f2bf(float f) {
    union { float f; unsigned int u; } cv; cv.f = f;
    unsigned int u = cv.u;
    unsigned int r = u + 0x7FFFu + ((u >> 16) & 1u);   // round-to-nearest-even
    return (unsigned short)(r >> 16);
}
static __device__ __forceinline__ unsigned int pack2(unsigned short a, unsigned short b) {
    return (unsigned int)a | ((unsigned int)b << 16);
}

// ---------- kernel 1: Wt fp32 -> bf16 ----------
__global__ void cvt_wt_kernel(const float* __restrict__ wt, unsigned short* __restrict__ out) {
    int t = blockIdx.x * blockDim.x + threadIdx.x;     // 16384 threads
    const float4* p = (const float4*)wt;
    float4 f0 = p[t * 2], f1 = p[t * 2 + 1];
    uint4 v;
    v.x = pack2(f2bf(f0.x), f2bf(f0.y));
    v.y = pack2(f2bf(f0.z), f2bf(f0.w));
    v.z = pack2(f2bf(f1.x), f2bf(f1.y));
    v.w = pack2(f2bf(f1.z), f2bf(f1.w));
    ((uint4*)out)[t] = v;
}

// ---------- kernel 2: batch (int64 OR int32) -> int32 ----------
__global__ void cvt_batch_kernel(const void* __restrict__ batch, int* __restrict__ out, int n) {
    const long long* p64 = (const long long*)batch;
    const int* p32 = (const int*)batch;
    bool is64 = ((unsigned long long)p64[n / 2 - 1]) < (1ull << 20);
    for (int i = blockIdx.x * blockDim.x + threadIdx.x; i < n; i += gridDim.x * blockDim.x)
        out[i] = is64 ? (int)p64[i] : p32[i];
}

// ---------- kernel 3: gate logits via bf16 MFMA (v2: no-spill, LDS-staged) ----------
// 128 rows/block, 4 waves x 32 rows. x staged coalesced -> swizzled LDS -> A-frags (64 VGPR).
// Same 64KB LDS reused as double-buffered Wt chunks (8 chunks of 64 h).
__global__ __launch_bounds__(256) void gate_kernel(
    const float* __restrict__ x, const unsigned short* __restrict__ wtb,
    const float* __restrict__ bt, const float* __restrict__ wg,
    const float* __restrict__ bg, float* __restrict__ logits, int n)
{
    __shared__ __align__(16) char lds[65536];
    const int tid = threadIdx.x;
    const int lane = tid & 63;
    const int wid = tid >> 6;
    const int l31 = lane & 31;
    const int g = lane >> 5;                    // k-half 0/1
    const long rowbase = (long)blockIdx.x * 128;

    // ---- phase 1: stage x[rowbase..rowbase+128) as bf16 into LDS, row-swizzled
    // thread t, iter it: float4 index idx = it*256+t -> row = idx>>6, col4 = idx&63 (coalesced 1KB/wave-instr)
    {
        const float4* xp = (const float4*)x;
#pragma unroll
        for (int it = 0; it < 32; ++it) {
            int idx = it * 256 + tid;
            int row = idx >> 6;
            int col4 = idx & 63;
            long grow = rowbase + row;
            float4 v = (grow < (long)n) ? xp[grow * 64 + col4] : make_float4(0.f, 0.f, 0.f, 0.f);
            unsigned int lo = pack2(f2bf(v.x), f2bf(v.y));
            unsigned int hi = pack2(f2bf(v.z), f2bf(v.w));
            int boff = row * 512 + ((col4 * 8) ^ ((row & 31) << 4));
            *(uint2*)(lds + boff) = make_uint2(lo, hi);
        }
    }
    __syncthreads();

    // ---- phase 2: A fragments from LDS (lane: row = wid*32+l31, k = kt*16+g*8..+7)
    short8 a[16];
    {
        const int row = wid * 32 + l31;
        const int rb = row * 512;
        const int sw = (row & 31) << 4;
#pragma unroll
        for (int kt = 0; kt < 16; ++kt)
            a[kt] = *(const short8*)(lds + rb + ((kt * 32 + g * 16) ^ sw));
    }
    __syncthreads();

    // ---- phase 3: 8 Wt chunks (64 h each, 32KB), double-buffered in same LDS
    float lp[16];
#pragma unroll
    for (int r = 0; r < 16; ++r) lp[r] = 0.f;

    const uint4* wtg = (const uint4*)wtb;       // 16B granules, 16384 total
    uint4 rg[8];

    // prologue: chunk0 -> LDS buf0; chunk1 -> regs
#pragma unroll
    for (int q = 0; q < 8; ++q) rg[q] = wtg[q * 256 + tid];
#pragma unroll
    for (int q = 0; q < 8; ++q) {
        int s = q * 256 + tid;
        int row = s >> 5, col = (s & 31) * 16;
        *(uint4*)(lds + row * 512 + (col ^ ((row & 31) << 4))) = rg[q];
    }
#pragma unroll
    for (int q = 0; q < 8; ++q) rg[q] = wtg[2048 + q * 256 + tid];
    __syncthreads();

    for (int c = 0; c < 8; ++c) {
        // write chunk c+1 (in regs) to the other buffer, then issue loads for c+2
        if (c + 1 < 8) {
            char* wb = lds + ((c + 1) & 1) * 32768;
#pragma unroll
            for (int q = 0; q < 8; ++q) {
                int s = q * 256 + tid;
                int row = s >> 5, col = (s & 31) * 16;
                *(uint4*)(wb + row * 512 + (col ^ ((row & 31) << 4))) = rg[q];
            }
            if (c + 2 < 8) {
#pragma unroll
                for (int q = 0; q < 8; ++q) rg[q] = wtg[(c + 2) * 2048 + q * 256 + tid];
            }
        }
        // compute chunk c from buf[c&1]
        const char* cb = lds + (c & 1) * 32768;
#pragma unroll
        for (int hg = 0; hg < 2; ++hg) {
            f32x16 acc;
#pragma unroll
            for (int r = 0; r < 16; ++r) acc[r] = 0.f;
            const int hr = hg * 32 + l31;
            const char* bb = cb + hr * 512;
            const int sw = (hr & 31) << 4;
#pragma unroll
            for (int kt = 0; kt < 16; ++kt) {
                short8 b = *(const short8*)(bb + ((kt * 32 + g * 16) ^ sw));
                acc = __builtin_amdgcn_mfma_f32_32x32x16_bf16(a[kt], b, acc, 0, 0, 0);
            }
            const int h = c * 64 + hg * 32 + l31;
            const float btv = bt[h];
            const float wgv = wg[h];
#pragma unroll
            for (int r = 0; r < 16; ++r) {
                float v = acc[r] + btv;
                float sp = fmaxf(v, 0.f) + __logf(1.f + __expf(-fabsf(v)));
                lp[r] = fmaf(sp, wgv, lp[r]);
            }
        }
        __syncthreads();
    }

    // reduce over the 32 h-lanes within each half, write logits
#pragma unroll
    for (int r = 0; r < 16; ++r) {
        float v = lp[r];
        v += __shfl_xor(v, 1);
        v += __shfl_xor(v, 2);
        v += __shfl_xor(v, 4);
        v += __shfl_xor(v, 8);
        v += __shfl_xor(v, 16);
        lp[r] = v;
    }
    if (l31 == 0) {
        const float bgv = bg[0];
#pragma unroll
        for (int r = 0; r < 16; ++r) {
            long row = rowbase + wid * 32 + 4 * g + (r & 3) + 8 * (r >> 2);  // C/D layout (m74/m101)
            if (row < (long)n) logits[row] = lp[r] + bgv;
        }
    }
}

// ---------- kernel 4: per-segment stats ----------
static __device__ __forceinline__ int lower_bound(const int* __restrict__ a, int n, int v) {
    int lo = 0, hi = n;
    while (lo < hi) { int mid = (lo + hi) >> 1; if (a[mid] < v) lo = mid + 1; else hi = mid; }
    return lo;
}

__global__ void segstats_kernel(const int* __restrict__ batch, const float* __restrict__ logits,
    float* __restrict__ segmax, float* __restrict__ segrs, float* __restrict__ seginv,
    int* __restrict__ segstart, int* __restrict__ segcnt, int n)
{
    const int b = blockIdx.x;
    __shared__ int sh_se[2];
    __shared__ float sh_red[4];
    const int tid = threadIdx.x;
    if (tid == 0) {
        sh_se[0] = lower_bound(batch, n, b);
        sh_se[1] = lower_bound(batch, n, b + 1);
    }
    __syncthreads();
    const int start = sh_se[0], end = sh_se[1];
    float m = -3.4e38f;
    for (int i = start + tid; i < end; i += 256) m = fmaxf(m, logits[i]);
#pragma unroll
    for (int mk = 1; mk <= 32; mk <<= 1) m = fmaxf(m, __shfl_xor(m, mk));
    if ((tid & 63) == 0) sh_red[tid >> 6] = m;
    __syncthreads();
    m = fmaxf(fmaxf(sh_red[0], sh_red[1]), fmaxf(sh_red[2], sh_red[3]));
    float s = 0.f;
    for (int i = start + tid; i < end; i += 256) s += __expf(logits[i] - m);
#pragma unroll
    for (int mk = 1; mk <= 32; mk <<= 1) s += __shfl_xor(s, mk);
    __syncthreads();
    if ((tid & 63) == 0) sh_red[tid >> 6] = s;
    __syncthreads();
    if (tid == 0) {
        s = sh_red[0] + sh_red[1] + sh_red[2] + sh_red[3];
        const int cnt = end - start;
        segmax[b] = m;
        segrs[b] = (s > 0.f) ? (1.f / s) : 0.f;
        seginv[b] = 1.f / (float)((cnt > 0) ? cnt : 1);
        segstart[b] = start;
        segcnt[b] = cnt;
    }
}

// ---------- kernel 5: fused per-node weight w' = attn + 1/cnt ----------
__global__ void weights_kernel(const int* __restrict__ batch, const float* __restrict__ logits,
    const float* __restrict__ segmax, const float* __restrict__ segrs,
    const float* __restrict__ seginv, float* __restrict__ wout, int n)
{
    for (int i = blockIdx.x * blockDim.x + threadIdx.x; i < n; i += gridDim.x * blockDim.x) {
        int b = batch[i];
        wout[i] = __expf(logits[i] - segmax[b]) * segrs[b] + seginv[b];
    }
}

// ---------- kernel 6: pooled output out[b,c] = sum_i w'[i] * x[i,c] ----------
__global__ __launch_bounds__(256) void pool_kernel(const float* __restrict__ x,
    const float* __restrict__ w, const int* __restrict__ segstart,
    const int* __restrict__ segcnt, float* __restrict__ out)
{
    const int b = blockIdx.x;
    const int c = threadIdx.x;
    const int start = segstart[b];
    const int cnt = segcnt[b];
    const float* xp = x + (size_t)start * CD + c;
    const float* wp = w + start;
    float acc = 0.f;
    int i = 0;
    for (; i + 8 <= cnt; i += 8) {
        float w0 = wp[i], w1 = wp[i+1], w2 = wp[i+2], w3 = wp[i+3];
        float w4 = wp[i+4], w5 = wp[i+5], w6 = wp[i+6], w7 = wp[i+7];
        float x0 = xp[(size_t)(i+0)*CD], x1 = xp[(size_t)(i+1)*CD];
        float x2 = xp[(size_t)(i+2)*CD], x3 = xp[(size_t)(i+3)*CD];
        float x4 = xp[(size_t)(i+4)*CD], x5 = xp[(size_t)(i+5)*CD];
        float x6 = xp[(size_t)(i+6)*CD], x7 = xp[(size_t)(i+7)*CD];
        acc = fmaf(w0,x0,fmaf(w1,x1,fmaf(w2,x2,fmaf(w3,x3,acc))));
        acc = fmaf(w4,x4,fmaf(w5,x5,fmaf(w6,x6,fmaf(w7,x7,acc))));
    }
    for (; i < cnt; ++i) acc = fmaf(wp[i], xp[(size_t)i*CD], acc);
    out[(size_t)b * CD + c] = acc;
}

// ---------- launcher ----------
extern "C" void kernel_launch(void* const* d_in, const int* in_sizes, int n_in,
                              void* d_out, int out_size, void* d_ws, size_t ws_size,
                              hipStream_t stream)
{
    const float* x  = (const float*)d_in[0];
    const void*  batch = d_in[1];
    const float* Wt = (const float*)d_in[3];
    const float* bt = (const float*)d_in[4];
    const float* Wg = (const float*)d_in[5];
    const float* bg = (const float*)d_in[6];
    float* out = (float*)d_out;
    const int n = in_sizes[1];            // 400000
    const int nseg = out_size / CD;       // 1024

    char* ws = (char*)d_ws;
    size_t off = 0;
    unsigned short* wtb = (unsigned short*)(ws + off); off += (size_t)HD * CD * 2;
    float* logits = (float*)(ws + off); off += (size_t)n * 4;
    float* wnode  = (float*)(ws + off); off += (size_t)n * 4;
    float* segmax = (float*)(ws + off); off += (size_t)nseg * 4;
    float* segrs  = (float*)(ws + off); off += (size_t)nseg * 4;
    float* seginv = (float*)(ws + off); off += (size_t)nseg * 4;
    int* segstart = (int*)(ws + off);   off += (size_t)nseg * 4;
    int* segcnt   = (int*)(ws + off);   off += (size_t)nseg * 4;
    int* batch32  = (int*)(ws + off);   off += (size_t)n * 4;

    hipLaunchKernelGGL(cvt_wt_kernel, dim3((HD * CD / 8) / 256), dim3(256), 0, stream, Wt, wtb);
    hipLaunchKernelGGL(cvt_batch_kernel, dim3(512), dim3(256), 0, stream, batch, batch32, n);
    hipLaunchKernelGGL(gate_kernel, dim3((n + 127) / 128), dim3(256), 0, stream,
                       x, wtb, bt, Wg, bg, logits, n);
    hipLaunchKernelGGL(segstats_kernel, dim3(nseg), dim3(256), 0, stream,
                       batch32, logits, segmax, segrs, seginv, segstart, segcnt, n);
    hipLaunchKernelGGL(weights_kernel, dim3(512), dim3(256), 0, stream,
                       batch32, logits, segmax, segrs, seginv, wnode, n);
    hipLaunchKernelGGL(pool_kernel, dim3(nseg), dim3(256), 0, stream,
                       x, wnode, segstart, segcnt, out);
}

// Round 3
// 370.128 us; speedup vs baseline: 1.4913x; 1.4913x over previous
//
#include <hip/hip_runtime.h>
#include <hip/hip_bf16.h>
#include <stdint.h>

typedef __attribute__((ext_vector_type(8))) short short8;
typedef __attribute__((ext_vector_type(16))) float f32x16;

#define CD 256   // channels
#define HD 512   // hidden

// ---------- helpers ----------
static __device__ __forceinline__ unsigned short f2bf(float f) {
    union { float f; unsigned int u; } cv; cv.f = f;
    unsigned int u = cv.u;
    unsigned int r = u + 0x7FFFu + ((u >> 16) & 1u);   // round-to-nearest-even
    return (unsigned short)(r >> 16);
}
static __device__ __forceinline__ unsigned int pack2(unsigned short a, unsigned short b) {
    return (unsigned int)a | ((unsigned int)b << 16);
}

// ---------- kernel 1: Wt fp32 -> bf16 ----------
__global__ void cvt_wt_kernel(const float* __restrict__ wt, unsigned short* __restrict__ out) {
    int t = blockIdx.x * blockDim.x + threadIdx.x;     // 16384 threads
    const float4* p = (const float4*)wt;
    float4 f0 = p[t * 2], f1 = p[t * 2 + 1];
    uint4 v;
    v.x = pack2(f2bf(f0.x), f2bf(f0.y));
    v.y = pack2(f2bf(f0.z), f2bf(f0.w));
    v.z = pack2(f2bf(f1.x), f2bf(f1.y));
    v.w = pack2(f2bf(f1.z), f2bf(f1.w));
    ((uint4*)out)[t] = v;
}

// ---------- kernel 2: batch (int64 OR int32) -> int32 ----------
__global__ void cvt_batch_kernel(const void* __restrict__ batch, int* __restrict__ out, int n) {
    const long long* p64 = (const long long*)batch;
    const int* p32 = (const int*)batch;
    bool is64 = ((unsigned long long)p64[n / 2 - 1]) < (1ull << 20);
    for (int i = blockIdx.x * blockDim.x + threadIdx.x; i < n; i += gridDim.x * blockDim.x)
        out[i] = is64 ? (int)p64[i] : p32[i];
}

// ---------- kernel 3: gate logits via bf16 MFMA (v3: global_load_lds Wt, no spill) ----------
// 128 rows/block, 4 waves x 32 rows. x staged coalesced -> swizzled LDS -> A-frags (64 VGPR).
// Wt: 16 chunks of 32 h (16KB), double-buffered via global_load_lds
// (linear LDS dest + inverse-swizzled per-lane global source + swizzled ds_read).
__global__ __launch_bounds__(256, 1) void gate_kernel(
    const float* __restrict__ x, const unsigned short* __restrict__ wtb,
    const float* __restrict__ bt, const float* __restrict__ wg,
    const float* __restrict__ bg, float* __restrict__ logits, int n)
{
    __shared__ __align__(16) char lds[65536];
    const int tid = threadIdx.x;
    const int lane = tid & 63;
    const int wid = tid >> 6;
    const int l31 = lane & 31;
    const int g = lane >> 5;                    // k-half 0/1
    const long rowbase = (long)blockIdx.x * 128;

    // ---- phase 1: stage x[rowbase..rowbase+128) as bf16 into LDS, row-swizzled.
    // wave-instr = one full 1KB row (64 float4), conflict-free 8B LDS writes.
    {
        const float4* xp = (const float4*)x;
#pragma unroll
        for (int it = 0; it < 32; ++it) {
            int idx = it * 256 + tid;
            int row = idx >> 6;
            int col4 = idx & 63;
            long grow = rowbase + row;
            float4 v = (grow < (long)n) ? xp[grow * 64 + col4] : make_float4(0.f, 0.f, 0.f, 0.f);
            __hip_bfloat162 lo = __float22bfloat162_rn(make_float2(v.x, v.y));
            __hip_bfloat162 hi = __float22bfloat162_rn(make_float2(v.z, v.w));
            int boff = row * 512 + ((col4 * 8) ^ ((row & 31) << 4));
            *(uint2*)(lds + boff) = make_uint2(*(unsigned int*)&lo, *(unsigned int*)&hi);
        }
    }
    __syncthreads();

    // ---- phase 2: A fragments from LDS (lane: row = wid*32+l31, k = kt*16+g*8..+7)
    short8 a[16];
    {
        const int row = wid * 32 + l31;
        const int rb = row * 512;
        const int sw = (row & 31) << 4;
#pragma unroll
        for (int kt = 0; kt < 16; ++kt)
            a[kt] = *(const short8*)(lds + rb + ((kt * 32 + g * 16) ^ sw));
    }
    __syncthreads();   // all waves' A-reads done before Wt staging overwrites lds

    // ---- phase 3: 16 Wt chunks (32 h, 16KB each), dbuf in lds[0..32KB)
    float lp[16];
#pragma unroll
    for (int r = 0; r < 16; ++r) lp[r] = 0.f;

    // per-lane source offsets: physical granule p = (wid*4+i)*64+lane holds
    // logical granule (rowc = p>>5, gc = (p&31)^rowc); src byte = rowc*512 + gc*16
    int soff[4];
#pragma unroll
    for (int i = 0; i < 4; ++i) {
        int p = (wid * 4 + i) * 64 + lane;
        int rc = p >> 5;
        int gcl = (p & 31) ^ (rc & 31);
        soff[i] = rc * 512 + gcl * 16;
    }
    const char* wtbb = (const char*)wtb;

#define STAGE(c)                                                                      \
    {                                                                                 \
        const char* src = wtbb + (c) * 16384;                                         \
        char* dst = lds + ((c) & 1) * 16384 + (wid * 4) * 1024;                       \
        _Pragma("unroll")                                                             \
        for (int i = 0; i < 4; ++i)                                                   \
            __builtin_amdgcn_global_load_lds(                                         \
                (const __attribute__((address_space(1))) unsigned int*)(src + soff[i]), \
                (__attribute__((address_space(3))) unsigned int*)(dst + i * 1024),    \
                16, 0, 0);                                                            \
    }

    STAGE(0);
    for (int c = 0; c < 16; ++c) {
        __syncthreads();                     // drains own stage(c) loads + guards dbuf reuse
        if (c + 1 < 16) STAGE(c + 1);
        const char* bb = lds + (c & 1) * 16384 + l31 * 512;
        f32x16 acc;
#pragma unroll
        for (int r = 0; r < 16; ++r) acc[r] = 0.f;
#pragma unroll
        for (int kt = 0; kt < 16; ++kt) {
            short8 b = *(const short8*)(bb + (((kt * 2 + g) ^ l31) * 16));
            acc = __builtin_amdgcn_mfma_f32_32x32x16_bf16(a[kt], b, acc, 0, 0, 0);
        }
        const int h = c * 32 + l31;
        const float btv = bt[h];
        const float wgv = wg[h];
#pragma unroll
        for (int r = 0; r < 16; ++r) {
            float v = acc[r] + btv;
            float sp = fmaxf(v, 0.f) + __logf(1.f + __expf(-fabsf(v)));
            lp[r] = fmaf(sp, wgv, lp[r]);
        }
    }
#undef STAGE

    // reduce over the 32 h-lanes within each half, write logits
#pragma unroll
    for (int r = 0; r < 16; ++r) {
        float v = lp[r];
        v += __shfl_xor(v, 1);
        v += __shfl_xor(v, 2);
        v += __shfl_xor(v, 4);
        v += __shfl_xor(v, 8);
        v += __shfl_xor(v, 16);
        lp[r] = v;
    }
    if (l31 == 0) {
        const float bgv = bg[0];
#pragma unroll
        for (int r = 0; r < 16; ++r) {
            long row = rowbase + wid * 32 + 4 * g + (r & 3) + 8 * (r >> 2);  // C/D layout (m74/m101)
            if (row < (long)n) logits[row] = lp[r] + bgv;
        }
    }
}

// ---------- kernel 4: per-segment stats ----------
static __device__ __forceinline__ int lower_bound(const int* __restrict__ a, int n, int v) {
    int lo = 0, hi = n;
    while (lo < hi) { int mid = (lo + hi) >> 1; if (a[mid] < v) lo = mid + 1; else hi = mid; }
    return lo;
}

__global__ void segstats_kernel(const int* __restrict__ batch, const float* __restrict__ logits,
    float* __restrict__ segmax, float* __restrict__ segrs, float* __restrict__ seginv,
    int* __restrict__ segstart, int* __restrict__ segcnt, int n)
{
    const int b = blockIdx.x;
    __shared__ int sh_se[2];
    __shared__ float sh_red[4];
    const int tid = threadIdx.x;
    if (tid == 0) {
        sh_se[0] = lower_bound(batch, n, b);
        sh_se[1] = lower_bound(batch, n, b + 1);
    }
    __syncthreads();
    const int start = sh_se[0], end = sh_se[1];
    float m = -3.4e38f;
    for (int i = start + tid; i < end; i += 256) m = fmaxf(m, logits[i]);
#pragma unroll
    for (int mk = 1; mk <= 32; mk <<= 1) m = fmaxf(m, __shfl_xor(m, mk));
    if ((tid & 63) == 0) sh_red[tid >> 6] = m;
    __syncthreads();
    m = fmaxf(fmaxf(sh_red[0], sh_red[1]), fmaxf(sh_red[2], sh_red[3]));
    float s = 0.f;
    for (int i = start + tid; i < end; i += 256) s += __expf(logits[i] - m);
#pragma unroll
    for (int mk = 1; mk <= 32; mk <<= 1) s += __shfl_xor(s, mk);
    __syncthreads();
    if ((tid & 63) == 0) sh_red[tid >> 6] = s;
    __syncthreads();
    if (tid == 0) {
        s = sh_red[0] + sh_red[1] + sh_red[2] + sh_red[3];
        const int cnt = end - start;
        segmax[b] = m;
        segrs[b] = (s > 0.f) ? (1.f / s) : 0.f;
        seginv[b] = 1.f / (float)((cnt > 0) ? cnt : 1);
        segstart[b] = start;
        segcnt[b] = cnt;
    }
}

// ---------- kernel 5: fused per-node weight w' = attn + 1/cnt ----------
__global__ void weights_kernel(const int* __restrict__ batch, const float* __restrict__ logits,
    const float* __restrict__ segmax, const float* __restrict__ segrs,
    const float* __restrict__ seginv, float* __restrict__ wout, int n)
{
    for (int i = blockIdx.x * blockDim.x + threadIdx.x; i < n; i += gridDim.x * blockDim.x) {
        int b = batch[i];
        wout[i] = __expf(logits[i] - segmax[b]) * segrs[b] + seginv[b];
    }
}

// ---------- kernel 6: pooled output out[b,c] = sum_i w'[i] * x[i,c] ----------
__global__ __launch_bounds__(256) void pool_kernel(const float* __restrict__ x,
    const float* __restrict__ w, const int* __restrict__ segstart,
    const int* __restrict__ segcnt, float* __restrict__ out)
{
    const int b = blockIdx.x;
    const int c = threadIdx.x;
    const int start = segstart[b];
    const int cnt = segcnt[b];
    const float* xp = x + (size_t)start * CD + c;
    const float* wp = w + start;
    float acc = 0.f;
    int i = 0;
    for (; i + 8 <= cnt; i += 8) {
        float w0 = wp[i], w1 = wp[i+1], w2 = wp[i+2], w3 = wp[i+3];
        float w4 = wp[i+4], w5 = wp[i+5], w6 = wp[i+6], w7 = wp[i+7];
        float x0 = xp[(size_t)(i+0)*CD], x1 = xp[(size_t)(i+1)*CD];
        float x2 = xp[(size_t)(i+2)*CD], x3 = xp[(size_t)(i+3)*CD];
        float x4 = xp[(size_t)(i+4)*CD], x5 = xp[(size_t)(i+5)*CD];
        float x6 = xp[(size_t)(i+6)*CD], x7 = xp[(size_t)(i+7)*CD];
        acc = fmaf(w0,x0,fmaf(w1,x1,fmaf(w2,x2,fmaf(w3,x3,acc))));
        acc = fmaf(w4,x4,fmaf(w5,x5,fmaf(w6,x6,fmaf(w7,x7,acc))));
    }
    for (; i < cnt; ++i) acc = fmaf(wp[i], xp[(size_t)i*CD], acc);
    out[(size_t)b * CD + c] = acc;
}

// ---------- launcher ----------
extern "C" void kernel_launch(void* const* d_in, const int* in_sizes, int n_in,
                              void* d_out, int out_size, void* d_ws, size_t ws_size,
                              hipStream_t stream)
{
    const float* x  = (const float*)d_in[0];
    const void*  batch = d_in[1];
    const float* Wt = (const float*)d_in[3];
    const float* bt = (const float*)d_in[4];
    const float* Wg = (const float*)d_in[5];
    const float* bg = (const float*)d_in[6];
    float* out = (float*)d_out;
    const int n = in_sizes[1];            // 400000
    const int nseg = out_size / CD;       // 1024

    char* ws = (char*)d_ws;
    size_t off = 0;
    unsigned short* wtb = (unsigned short*)(ws + off); off += (size_t)HD * CD * 2;
    float* logits = (float*)(ws + off); off += (size_t)n * 4;
    float* wnode  = (float*)(ws + off); off += (size_t)n * 4;
    float* segmax = (float*)(ws + off); off += (size_t)nseg * 4;
    float* segrs  = (float*)(ws + off); off += (size_t)nseg * 4;
    float* seginv = (float*)(ws + off); off += (size_t)nseg * 4;
    int* segstart = (int*)(ws + off);   off += (size_t)nseg * 4;
    int* segcnt   = (int*)(ws + off);   off += (size_t)nseg * 4;
    int* batch32  = (int*)(ws + off);   off += (size_t)n * 4;

    hipLaunchKernelGGL(cvt_wt_kernel, dim3((HD * CD / 8) / 256), dim3(256), 0, stream, Wt, wtb);
    hipLaunchKernelGGL(cvt_batch_kernel, dim3(512), dim3(256), 0, stream, batch, batch32, n);
    hipLaunchKernelGGL(gate_kernel, dim3((n + 127) / 128), dim3(256), 0, stream,
                       x, wtb, bt, Wg, bg, logits, n);
    hipLaunchKernelGGL(segstats_kernel, dim3(nseg), dim3(256), 0, stream,
                       batch32, logits, segmax, segrs, seginv, segstart, segcnt, n);
    hipLaunchKernelGGL(weights_kernel, dim3(512), dim3(256), 0, stream,
                       batch32, logits, segmax, segrs, seginv, wnode, n);
    hipLaunchKernelGGL(pool_kernel, dim3(nseg), dim3(256), 0, stream,
                       x, wnode, segstart, segcnt, out);
}

// Round 4
// 310.558 us; speedup vs baseline: 1.7774x; 1.1918x over previous
//
#include <hip/hip_runtime.h>
#include <hip/hip_bf16.h>
#include <stdint.h>

typedef __attribute__((ext_vector_type(8))) short short8;
typedef __attribute__((ext_vector_type(16))) float f32x16;

#define CD 256   // channels
#define HD 512   // hidden

// ---------- helpers ----------
static __device__ __forceinline__ unsigned short f2bf(float f) {
    union { float f; unsigned int u; } cv; cv.f = f;
    unsigned int u = cv.u;
    unsigned int r = u + 0x7FFFu + ((u >> 16) & 1u);   // round-to-nearest-even
    return (unsigned short)(r >> 16);
}
static __device__ __forceinline__ unsigned int pack2(unsigned short a, unsigned short b) {
    return (unsigned int)a | ((unsigned int)b << 16);
}

// ---------- kernel 1: Wt fp32 -> bf16 ----------
__global__ void cvt_wt_kernel(const float* __restrict__ wt, unsigned short* __restrict__ out) {
    int t = blockIdx.x * blockDim.x + threadIdx.x;     // 16384 threads
    const float4* p = (const float4*)wt;
    float4 f0 = p[t * 2], f1 = p[t * 2 + 1];
    uint4 v;
    v.x = pack2(f2bf(f0.x), f2bf(f0.y));
    v.y = pack2(f2bf(f0.z), f2bf(f0.w));
    v.z = pack2(f2bf(f1.x), f2bf(f1.y));
    v.w = pack2(f2bf(f1.z), f2bf(f1.w));
    ((uint4*)out)[t] = v;
}

// ---------- kernel 2: batch (int64 OR int32) -> int32 ----------
__global__ void cvt_batch_kernel(const void* __restrict__ batch, int* __restrict__ out, int n) {
    const long long* p64 = (const long long*)batch;
    const int* p32 = (const int*)batch;
    bool is64 = ((unsigned long long)p64[n / 2 - 1]) < (1ull << 20);
    for (int i = blockIdx.x * blockDim.x + threadIdx.x; i < n; i += gridDim.x * blockDim.x)
        out[i] = is64 ? (int)p64[i] : p32[i];
}

// ---------- kernel 3: gate logits via bf16 MFMA (v4: direct-global A, 32KB LDS) ----------
// 128 rows/block, 4 waves x 32 rows. A-frags loaded per-lane straight from x
// (32B/lane/kt -> full 64B-line utilization), cvt to bf16 in-reg.
// Wt: 16 chunks of 32 h (16KB), double-buffered via global_load_lds
// (linear LDS dest + inverse-swizzled per-lane global source + swizzled ds_read).
__global__ __launch_bounds__(256, 3) void gate_kernel(
    const float* __restrict__ x, const unsigned short* __restrict__ wtb,
    const float* __restrict__ bt, const float* __restrict__ wg,
    const float* __restrict__ bg, float* __restrict__ logits, int n)
{
    __shared__ __align__(16) char lds[32768];
    const int tid = threadIdx.x;
    const int lane = tid & 63;
    const int wid = tid >> 6;
    const int l31 = lane & 31;
    const int g = lane >> 5;                    // k-half 0/1
    const long rowbase = (long)blockIdx.x * 128;

    // per-lane Wt source offsets: physical granule p holds logical (rc, (p&31)^rc)
    int soff[4];
#pragma unroll
    for (int i = 0; i < 4; ++i) {
        int p = (wid * 4 + i) * 64 + lane;
        int rc = p >> 5;
        int gcl = (p & 31) ^ (rc & 31);
        soff[i] = rc * 512 + gcl * 16;
    }
    const char* wtbb = (const char*)wtb;

#define STAGE(c)                                                                      \
    {                                                                                 \
        const char* src = wtbb + (c) * 16384;                                         \
        char* dst = lds + ((c) & 1) * 16384 + (wid * 4) * 1024;                       \
        _Pragma("unroll")                                                             \
        for (int i = 0; i < 4; ++i)                                                   \
            __builtin_amdgcn_global_load_lds(                                         \
                (const __attribute__((address_space(1))) unsigned int*)(src + soff[i]), \
                (__attribute__((address_space(3))) unsigned int*)(dst + i * 1024),    \
                16, 0, 0);                                                            \
    }

    STAGE(0);

    // A fragments: direct global loads (row = rowbase + wid*32 + l31, k = kt*16+g*8..+7)
    short8 a[16];
    {
        const long row = rowbase + wid * 32 + l31;
        const bool ok = row < (long)n;
        const float4* xr = (const float4*)(x + row * 256) + g * 2;
#pragma unroll
        for (int kt = 0; kt < 16; ++kt) {
            float4 f0 = ok ? xr[kt * 4]     : make_float4(0.f, 0.f, 0.f, 0.f);
            float4 f1 = ok ? xr[kt * 4 + 1] : make_float4(0.f, 0.f, 0.f, 0.f);
            __hip_bfloat162 p0 = __float22bfloat162_rn(make_float2(f0.x, f0.y));
            __hip_bfloat162 p1 = __float22bfloat162_rn(make_float2(f0.z, f0.w));
            __hip_bfloat162 p2 = __float22bfloat162_rn(make_float2(f1.x, f1.y));
            __hip_bfloat162 p3 = __float22bfloat162_rn(make_float2(f1.z, f1.w));
            union { uint4 u; short8 s; } cv;
            cv.u = make_uint4(*(unsigned int*)&p0, *(unsigned int*)&p1,
                              *(unsigned int*)&p2, *(unsigned int*)&p3);
            a[kt] = cv.s;
        }
    }

    float lp[16];
#pragma unroll
    for (int r = 0; r < 16; ++r) lp[r] = 0.f;

    for (int c = 0; c < 16; ++c) {
        __syncthreads();                     // drains stage(c) (+ A-loads on c=0), guards dbuf
        if (c + 1 < 16) STAGE(c + 1);
        const char* bb = lds + (c & 1) * 16384 + l31 * 512;
        f32x16 acc;
#pragma unroll
        for (int r = 0; r < 16; ++r) acc[r] = 0.f;
#pragma unroll
        for (int kt = 0; kt < 16; ++kt) {
            short8 b = *(const short8*)(bb + (((kt * 2 + g) ^ l31) * 16));
            acc = __builtin_amdgcn_mfma_f32_32x32x16_bf16(a[kt], b, acc, 0, 0, 0);
        }
        const int h = c * 32 + l31;
        const float btv = bt[h];
        const float wgv = wg[h];
#pragma unroll
        for (int r = 0; r < 16; ++r) {
            float v = acc[r] + btv;
            float sp = fmaxf(v, 0.f) + __logf(1.f + __expf(-fabsf(v)));
            lp[r] = fmaf(sp, wgv, lp[r]);
        }
    }
#undef STAGE

    // reduce over the 32 h-lanes within each half, write logits
#pragma unroll
    for (int r = 0; r < 16; ++r) {
        float v = lp[r];
        v += __shfl_xor(v, 1);
        v += __shfl_xor(v, 2);
        v += __shfl_xor(v, 4);
        v += __shfl_xor(v, 8);
        v += __shfl_xor(v, 16);
        lp[r] = v;
    }
    if (l31 == 0) {
        const float bgv = bg[0];
#pragma unroll
        for (int r = 0; r < 16; ++r) {
            long row = rowbase + wid * 32 + 4 * g + (r & 3) + 8 * (r >> 2);  // C/D layout (m74/m101)
            if (row < (long)n) logits[row] = lp[r] + bgv;
        }
    }
}

// ---------- kernel 4: per-segment stats ----------
static __device__ __forceinline__ int lower_bound(const int* __restrict__ a, int n, int v) {
    int lo = 0, hi = n;
    while (lo < hi) { int mid = (lo + hi) >> 1; if (a[mid] < v) lo = mid + 1; else hi = mid; }
    return lo;
}

__global__ void segstats_kernel(const int* __restrict__ batch, const float* __restrict__ logits,
    float* __restrict__ segmax, float* __restrict__ segrs, float* __restrict__ seginv,
    int* __restrict__ segstart, int* __restrict__ segcnt, int n)
{
    const int b = blockIdx.x;
    __shared__ int sh_se[2];
    __shared__ float sh_red[4];
    const int tid = threadIdx.x;
    if (tid == 0) {
        sh_se[0] = lower_bound(batch, n, b);
        sh_se[1] = lower_bound(batch, n, b + 1);
    }
    __syncthreads();
    const int start = sh_se[0], end = sh_se[1];
    float m = -3.4e38f;
    for (int i = start + tid; i < end; i += 256) m = fmaxf(m, logits[i]);
#pragma unroll
    for (int mk = 1; mk <= 32; mk <<= 1) m = fmaxf(m, __shfl_xor(m, mk));
    if ((tid & 63) == 0) sh_red[tid >> 6] = m;
    __syncthreads();
    m = fmaxf(fmaxf(sh_red[0], sh_red[1]), fmaxf(sh_red[2], sh_red[3]));
    float s = 0.f;
    for (int i = start + tid; i < end; i += 256) s += __expf(logits[i] - m);
#pragma unroll
    for (int mk = 1; mk <= 32; mk <<= 1) s += __shfl_xor(s, mk);
    __syncthreads();
    if ((tid & 63) == 0) sh_red[tid >> 6] = s;
    __syncthreads();
    if (tid == 0) {
        s = sh_red[0] + sh_red[1] + sh_red[2] + sh_red[3];
        const int cnt = end - start;
        segmax[b] = m;
        segrs[b] = (s > 0.f) ? (1.f / s) : 0.f;
        seginv[b] = 1.f / (float)((cnt > 0) ? cnt : 1);
        segstart[b] = start;
        segcnt[b] = cnt;
    }
}

// ---------- kernel 5: pooled output, weights computed inline via LDS stage ----------
// out[b,c] = sum_i (exp(logit_i - smax)*srs + 1/cnt) * x[i,c]
__global__ __launch_bounds__(256) void pool_kernel(const float* __restrict__ x,
    const float* __restrict__ logits, const float* __restrict__ segmax,
    const float* __restrict__ segrs, const float* __restrict__ seginv,
    const int* __restrict__ segstart, const int* __restrict__ segcnt,
    float* __restrict__ out)
{
    __shared__ float wsh[1024];
    const int b = blockIdx.x;
    const int c = threadIdx.x;
    const int start = segstart[b];
    const int cnt = segcnt[b];
    const float smax = segmax[b], srs = segrs[b], sinv = seginv[b];
    float acc = 0.f;
    for (int base = 0; base < cnt; base += 1024) {
        const int m = min(cnt - base, 1024);
        __syncthreads();
        for (int i = c; i < m; i += 256)
            wsh[i] = __expf(logits[start + base + i] - smax) * srs + sinv;
        __syncthreads();
        const float* xp = x + (size_t)(start + base) * CD + c;
        int i = 0;
        for (; i + 8 <= m; i += 8) {
            float x0 = xp[(size_t)(i+0)*CD], x1 = xp[(size_t)(i+1)*CD];
            float x2 = xp[(size_t)(i+2)*CD], x3 = xp[(size_t)(i+3)*CD];
            float x4 = xp[(size_t)(i+4)*CD], x5 = xp[(size_t)(i+5)*CD];
            float x6 = xp[(size_t)(i+6)*CD], x7 = xp[(size_t)(i+7)*CD];
            acc = fmaf(wsh[i+0],x0,fmaf(wsh[i+1],x1,fmaf(wsh[i+2],x2,fmaf(wsh[i+3],x3,acc))));
            acc = fmaf(wsh[i+4],x4,fmaf(wsh[i+5],x5,fmaf(wsh[i+6],x6,fmaf(wsh[i+7],x7,acc))));
        }
        for (; i < m; ++i) acc = fmaf(wsh[i], xp[(size_t)i*CD], acc);
    }
    out[(size_t)b * CD + c] = acc;
}

// ---------- launcher ----------
extern "C" void kernel_launch(void* const* d_in, const int* in_sizes, int n_in,
                              void* d_out, int out_size, void* d_ws, size_t ws_size,
                              hipStream_t stream)
{
    const float* x  = (const float*)d_in[0];
    const void*  batch = d_in[1];
    const float* Wt = (const float*)d_in[3];
    const float* bt = (const float*)d_in[4];
    const float* Wg = (const float*)d_in[5];
    const float* bg = (const float*)d_in[6];
    float* out = (float*)d_out;
    const int n = in_sizes[1];            // 400000
    const int nseg = out_size / CD;       // 1024

    char* ws = (char*)d_ws;
    size_t off = 0;
    unsigned short* wtb = (unsigned short*)(ws + off); off += (size_t)HD * CD * 2;
    float* logits = (float*)(ws + off); off += (size_t)n * 4;
    float* segmax = (float*)(ws + off); off += (size_t)nseg * 4;
    float* segrs  = (float*)(ws + off); off += (size_t)nseg * 4;
    float* seginv = (float*)(ws + off); off += (size_t)nseg * 4;
    int* segstart = (int*)(ws + off);   off += (size_t)nseg * 4;
    int* segcnt   = (int*)(ws + off);   off += (size_t)nseg * 4;
    int* batch32  = (int*)(ws + off);   off += (size_t)n * 4;

    hipLaunchKernelGGL(cvt_wt_kernel, dim3((HD * CD / 8) / 256), dim3(256), 0, stream, Wt, wtb);
    hipLaunchKernelGGL(cvt_batch_kernel, dim3(512), dim3(256), 0, stream, batch, batch32, n);
    hipLaunchKernelGGL(gate_kernel, dim3((n + 127) / 128), dim3(256), 0, stream,
                       x, wtb, bt, Wg, bg, logits, n);
    hipLaunchKernelGGL(segstats_kernel, dim3(nseg), dim3(256), 0, stream,
                       batch32, logits, segmax, segrs, seginv, segstart, segcnt, n);
    hipLaunchKernelGGL(pool_kernel, dim3(nseg), dim3(256), 0, stream,
                       x, logits, segmax, segrs, seginv, segstart, segcnt, out);
}